// Round 1
// baseline (154.229 us; speedup 1.0000x reference)
//
#include <hip/hip_runtime.h>

// The reference's softmax is over a trailing singleton axis -> all ones;
// mean over heads of ones -> ones. Output is a constant (B1, B2) = 1.0f
// matrix for any finite input. Kernel = vectorized constant fill.

__global__ void fill_ones_f32(float4* __restrict__ out4, int n4,
                              float* __restrict__ out_tail, int tail_start, int n) {
    int i = blockIdx.x * blockDim.x + threadIdx.x;
    if (i < n4) {
        out4[i] = make_float4(1.0f, 1.0f, 1.0f, 1.0f);
    }
    // Tail handling (n not divisible by 4) — first few threads cover it.
    int t = tail_start + i;
    if (i < 4 && t < n) {
        out_tail[t] = 1.0f;
    }
}

extern "C" void kernel_launch(void* const* d_in, const int* in_sizes, int n_in,
                              void* d_out, int out_size, void* d_ws, size_t ws_size,
                              hipStream_t stream) {
    (void)d_in; (void)in_sizes; (void)n_in; (void)d_ws; (void)ws_size;

    float* out = (float*)d_out;
    int n = out_size;          // 2048 * 2048 = 4194304
    int n4 = n / 4;            // 1048576 float4 stores
    int tail_start = n4 * 4;

    const int block = 256;
    int grid = (n4 + block - 1) / block;
    if (grid < 1) grid = 1;

    fill_ones_f32<<<grid, block, 0, stream>>>((float4*)out, n4, out, tail_start, n);
}